// Round 4
// baseline (120.422 us; speedup 1.0000x reference)
//
#include <hip/hip_runtime.h>

typedef float f4 __attribute__((ext_vector_type(4)));
typedef unsigned short us8 __attribute__((ext_vector_type(8)));

#define N_SEL   8192
#define N_FEAT  256
#define K_SUB   256
#define N_PERS  4
#define E_FULL  262144
#define E_RAW   262144
#define N_TOTAL 8192
#define EPSILON 0.5f
#define LAMB1   0.5f

// Workspace layout (~6.75 MB):
#define WS_SCORE_OFF    (128 * 1024)            // score[K_SUB] f32
#define WS_ROWCNT_OFF   (132 * 1024)            // row_cnt[N_TOTAL] i32
#define WS_ROWSTART_OFF (164 * 1024)            // row_start[N_TOTAL] i32
#define WS_ROWFILL_OFF  (196 * 1024)            // row_fill[N_TOTAL] i32
#define WS_CNT_OFF      (228 * 1024)            // pass counter i32
#define WS_XB_OFF       (256 * 1024)            // xb[N_SEL][256] bf16 (4 MB)
#define WS_BUCKET_OFF   (WS_XB_OFF + 4*1024*1024)        // bucket[E_RAW] u16 (512 KB)
#define WS_LIST_OFF     (WS_BUCKET_OFF + 512*1024)       // list[E_FULL] int2 (2 MB)

#define B2F(s) __uint_as_float(((unsigned)(s)) << 16)

static __device__ __forceinline__ unsigned short f2b(float f) {
    unsigned u = __float_as_uint(f);
    unsigned r = u + 0x7FFFu + ((u >> 16) & 1u);   // RNE
    return (unsigned short)(r >> 16);
}

// ---- K0: zero the small counters (runtime fillBuffer is garbage; do it ourselves) ----
__global__ __launch_bounds__(256) void init_kernel(int* __restrict__ row_cnt,
                                                   int* __restrict__ row_fill,
                                                   int* __restrict__ cnt) {
    int t = blockIdx.x * 256 + threadIdx.x;
    row_cnt[t] = 0;
    row_fill[t] = 0;
    if (t == 0) *cnt = 0;
}

// ---- K1: inverse norms + bf16 convert + score + raw-edge row counting ----
__global__ __launch_bounds__(256) void prep_kernel(const f4* __restrict__ x4,
                                                   const f4* __restrict__ w4,
                                                   float* __restrict__ invn,
                                                   ushort4* __restrict__ xb,
                                                   const float* __restrict__ s,
                                                   const int* __restrict__ belong,
                                                   float* __restrict__ score,
                                                   const int* __restrict__ re,
                                                   int* __restrict__ row_cnt) {
    __shared__ float sv[K_SUB];
    __shared__ int bv[K_SUB];
    int gid = blockIdx.x * 256 + threadIdx.x;
    int wave = gid >> 6;
    int lane = threadIdx.x & 63;
    int n = wave >> 2;
    int p = wave & 3;
    f4 xv = x4[(size_t)n * 64 + lane];
    f4 wv = w4[p * 64 + lane];
    if (p == 0) {
        ushort4 b;
        b.x = f2b(xv.x); b.y = f2b(xv.y); b.z = f2b(xv.z); b.w = f2b(xv.w);
        xb[(size_t)n * 64 + lane] = b;
    }
    f4 h = xv * wv;
    float ss = h.x * h.x + h.y * h.y + h.z * h.z + h.w * h.w;
    #pragma unroll
    for (int off = 32; off; off >>= 1) ss += __shfl_xor(ss, off);
    if (lane == 0) invn[n * 4 + p] = 1.0f / (sqrtf(ss) + 1e-12f);

    // raw-edge destination-row histogram (first E_RAW threads)
    if (gid < E_RAW) atomicAdd(&row_cnt[re[gid]], 1);

    if (blockIdx.x == 0) {
        int t = threadIdx.x;
        sv[t] = s[t];
        bv[t] = belong[t];
        __syncthreads();
        int myb = bv[t];
        float sum = 0.0f;
        for (int k = 0; k < K_SUB; ++k)
            if (bv[k] == myb) sum += sv[k];
        score[t] = sv[t] / sum;
    }
}

// ---- K2: exclusive prefix scan of row_cnt -> row_start (one block) ----
__global__ __launch_bounds__(256) void scan_kernel(const int* __restrict__ row_cnt,
                                                   int* __restrict__ row_start) {
    __shared__ int sc[256];
    int t = threadIdx.x;
    int base = t * 32;
    int local[32];
    int sum = 0;
    #pragma unroll
    for (int k = 0; k < 32; ++k) { local[k] = sum; sum += row_cnt[base + k]; }
    sc[t] = sum;
    __syncthreads();
    for (int off = 1; off < 256; off <<= 1) {
        int v = (t >= off) ? sc[t - off] : 0;
        __syncthreads();
        sc[t] += v;
        __syncthreads();
    }
    int blockExcl = sc[t] - sum;
    #pragma unroll
    for (int k = 0; k < 32; ++k) row_start[base + k] = blockExcl + local[k];
}

// ---- K3: scatter raw edges into per-row buckets ----
__global__ __launch_bounds__(256) void bucket_kernel(const int* __restrict__ re,
                                                     const int* __restrict__ row_start,
                                                     int* __restrict__ row_fill,
                                                     unsigned short* __restrict__ bucket) {
    int t = blockIdx.x * 256 + threadIdx.x;
    if (t < E_RAW) {
        int u = re[t];
        int v = re[E_RAW + t];
        int pos = row_start[u] + atomicAdd(&row_fill[u], 1);
        bucket[pos] = (unsigned short)v;
    }
}

// ---- K4: one block per output row: compose row in LDS (raw edges) + single
//          full-line write pass; then 32 masked-cosine edges per block ----
__global__ __launch_bounds__(256) void compose_kernel(f4* __restrict__ out4,
                                                      const us8* __restrict__ xb8,
                                                      const f4* __restrict__ w4,
                                                      const int* __restrict__ fe,
                                                      const int* __restrict__ sel_batch,
                                                      const f4* __restrict__ invn4,
                                                      const float* __restrict__ score,
                                                      const int* __restrict__ row_cnt,
                                                      const int* __restrict__ row_start,
                                                      const unsigned short* __restrict__ bucket,
                                                      int2* __restrict__ list,
                                                      int* __restrict__ cnt) {
    __shared__ float lds[N_TOTAL];          // 32 KB row image
    int b = blockIdx.x;                      // row id
    int t = threadIdx.x;
    int lane = t & 63;
    int l16  = lane & 15;
    int g    = lane >> 4;
    int w    = t >> 6;

    // per-lane squared weights for cosine (dims [l16*16, l16*16+16), 4 persp)
    float q0[16], q1[16], q2[16], q3[16];
    #pragma unroll
    for (int gg = 0; gg < 4; ++gg) {
        f4 w0 = w4[0 * 64 + l16 * 4 + gg];
        f4 w1 = w4[1 * 64 + l16 * 4 + gg];
        f4 w2 = w4[2 * 64 + l16 * 4 + gg];
        f4 w3 = w4[3 * 64 + l16 * 4 + gg];
        q0[gg*4+0]=w0.x*w0.x; q0[gg*4+1]=w0.y*w0.y; q0[gg*4+2]=w0.z*w0.z; q0[gg*4+3]=w0.w*w0.w;
        q1[gg*4+0]=w1.x*w1.x; q1[gg*4+1]=w1.y*w1.y; q1[gg*4+2]=w1.z*w1.z; q1[gg*4+3]=w1.w*w1.w;
        q2[gg*4+0]=w2.x*w2.x; q2[gg*4+1]=w2.y*w2.y; q2[gg*4+2]=w2.z*w2.z; q2[gg*4+3]=w2.w*w2.w;
        q3[gg*4+0]=w3.x*w3.x; q3[gg*4+1]=w3.y*w3.y; q3[gg*4+2]=w3.z*w3.z; q3[gg*4+3]=w3.w*w3.w;
    }

    // phase A: zero row image
    f4* lds4 = (f4*)lds;
    f4 z = (f4)0.0f;
    #pragma unroll
    for (int it = 0; it < 8; ++it) lds4[it * 256 + t] = z;
    __syncthreads();

    // phase B: apply this row's raw edges (LDS atomics; +0.5 exact -> deterministic)
    int rc = row_cnt[b];
    int rs = row_start[b];
    for (int k = t; k < rc; k += 256)
        atomicAdd(&lds[bucket[rs + k]], 1.0f - LAMB1);
    __syncthreads();

    // phase C: single full-line write pass of the row
    size_t obase = (size_t)b * (N_TOTAL / 4);
    #pragma unroll
    for (int it = 0; it < 8; ++it)
        out4[obase + it * 256 + t] = lds4[it * 256 + t];

    // phase D: 32 masked-cosine edges for this block (overlaps store drain)
    int ebase = b * 32 + w * 8;
    #pragma unroll
    for (int it = 0; it < 2; ++it) {
        int e = ebase + it * 4 + g;
        int i = fe[e];
        int j = fe[E_FULL + e];
        const us8* ri = xb8 + (size_t)i * 32;
        const us8* rj = xb8 + (size_t)j * 32;
        us8 xi0 = ri[2 * l16], xi1 = ri[2 * l16 + 1];
        us8 xj0 = rj[2 * l16], xj1 = rj[2 * l16 + 1];

        float a0 = 0.f, a1 = 0.f, a2 = 0.f, a3 = 0.f;
        #pragma unroll
        for (int k = 0; k < 8; ++k) {
            float p0 = B2F(xi0[k]) * B2F(xj0[k]);
            float p1 = B2F(xi1[k]) * B2F(xj1[k]);
            a0 = fmaf(p1, q0[k + 8], fmaf(p0, q0[k], a0));
            a1 = fmaf(p1, q1[k + 8], fmaf(p0, q1[k], a1));
            a2 = fmaf(p1, q2[k + 8], fmaf(p0, q2[k], a2));
            a3 = fmaf(p1, q3[k + 8], fmaf(p0, q3[k], a3));
        }
        f4 ii = invn4[i];
        f4 ij = invn4[j];
        float v = a0 * (ii.x * ij.x) + a1 * (ii.y * ij.y) +
                  a2 * (ii.z * ij.z) + a3 * (ii.w * ij.w);
        v += __shfl_xor(v, 1);
        v += __shfl_xor(v, 2);
        v += __shfl_xor(v, 4);
        v += __shfl_xor(v, 8);

        if (l16 == 0 && i != j) {
            v *= 0.25f;
            if (v > EPSILON) {
                float val = v * score[sel_batch[i]] * LAMB1;
                int idx = atomicAdd(cnt, 1);
                int2 ent;
                ent.x = (i << 13) | j;
                ent.y = __float_as_int(val);
                list[idx] = ent;
            }
        }
    }
}

// ---- K5: dedup passing learned edges (mask .set semantics) + scatter ----
__global__ __launch_bounds__(256) void finalize_kernel(const int2* __restrict__ list,
                                                       const int* __restrict__ cnt,
                                                       const int* __restrict__ sel_map,
                                                       float* __restrict__ out) {
    int t = blockIdx.x * 256 + threadIdx.x;
    int n = *cnt;
    if (t >= n) return;
    int2 ek = list[t];
    for (int l = 0; l < t; ++l)
        if (list[l].x == ek.x) return;      // first occurrence wins; dups identical
    int i = ek.x >> 13;
    int j = ek.x & (N_SEL - 1);
    atomicAdd(&out[(size_t)sel_map[i] * N_TOTAL + sel_map[j]], __int_as_float(ek.y));
}

extern "C" void kernel_launch(void* const* d_in, const int* in_sizes, int n_in,
                              void* d_out, int out_size, void* d_ws, size_t ws_size,
                              hipStream_t stream) {
    const float* x         = (const float*)d_in[0];
    const float* mw        = (const float*)d_in[1];
    const int* sel_batch   = (const int*)d_in[2];
    const int* sel_map     = (const int*)d_in[3];
    const int* sel_belong  = (const int*)d_in[4];
    const float* sel_score = (const float*)d_in[5];
    const int* fe          = (const int*)d_in[6];
    const int* re          = (const int*)d_in[7];
    float* out             = (float*)d_out;

    char* ws        = (char*)d_ws;
    float* invn     = (float*)ws;
    float* score    = (float*)(ws + WS_SCORE_OFF);
    int* row_cnt    = (int*)(ws + WS_ROWCNT_OFF);
    int* row_start  = (int*)(ws + WS_ROWSTART_OFF);
    int* row_fill   = (int*)(ws + WS_ROWFILL_OFF);
    int* cnt        = (int*)(ws + WS_CNT_OFF);
    ushort4* xb     = (ushort4*)(ws + WS_XB_OFF);
    unsigned short* bucket = (unsigned short*)(ws + WS_BUCKET_OFF);
    int2* list      = (int2*)(ws + WS_LIST_OFF);

    init_kernel<<<N_TOTAL / 256, 256, 0, stream>>>(row_cnt, row_fill, cnt);
    prep_kernel<<<8192, 256, 0, stream>>>(
        (const f4*)x, (const f4*)mw, invn, xb, sel_score, sel_belong, score,
        re, row_cnt);
    scan_kernel<<<1, 256, 0, stream>>>(row_cnt, row_start);
    bucket_kernel<<<E_RAW / 256, 256, 0, stream>>>(re, row_start, row_fill, bucket);
    compose_kernel<<<N_TOTAL, 256, 0, stream>>>(
        (f4*)out, (const us8*)xb, (const f4*)mw, fe, sel_batch,
        (const f4*)invn, score, row_cnt, row_start, bucket, list, cnt);
    finalize_kernel<<<E_FULL / 256, 256, 0, stream>>>(list, cnt, sel_map, out);
}

// Round 5
// 109.747 us; speedup vs baseline: 1.0973x; 1.0973x over previous
//
#include <hip/hip_runtime.h>

typedef float f4 __attribute__((ext_vector_type(4)));
typedef unsigned short us8 __attribute__((ext_vector_type(8)));

#define N_SEL   8192
#define N_FEAT  256
#define K_SUB   256
#define N_PERS  4
#define E_FULL  262144
#define E_RAW   262144
#define N_TOTAL 8192
#define EPSILON 0.5f
#define LAMB1   0.5f
#define ROW_CAP 128

// Workspace layout (~8.3 MB):
#define WS_SCORE_OFF  (128 * 1024)                    // score[K_SUB] f32
#define WS_CNT_OFF    (132 * 1024)                    // pass counter i32
#define WS_FILL_OFF   (136 * 1024)                    // row_fill[N_TOTAL] i32 (32 KB)
#define WS_XB_OFF     (256 * 1024)                    // xb[N_SEL][256] bf16 (4 MB)
#define WS_BUCKET_OFF (WS_XB_OFF + 4 * 1024 * 1024)   // bucket[N_TOTAL][128] u16 (2 MB)
#define WS_LIST_OFF   (WS_BUCKET_OFF + 2 * 1024 * 1024) // list[E_FULL] int2 (2 MB)

#define B2F(s) __uint_as_float(((unsigned)(s)) << 16)

static __device__ __forceinline__ unsigned short f2b(float f) {
    unsigned u = __float_as_uint(f);
    unsigned r = u + 0x7FFFu + ((u >> 16) & 1u);   // RNE
    return (unsigned short)(r >> 16);
}

// ---- K1: inverse norms + bf16 convert + score + row_fill/cnt zero ----
__global__ __launch_bounds__(256) void prep_kernel(const f4* __restrict__ x4,
                                                   const f4* __restrict__ w4,
                                                   float* __restrict__ invn,
                                                   ushort4* __restrict__ xb,
                                                   const float* __restrict__ s,
                                                   const int* __restrict__ belong,
                                                   float* __restrict__ score,
                                                   int* __restrict__ row_fill,
                                                   int* __restrict__ cnt) {
    __shared__ float sv[K_SUB];
    __shared__ int bv[K_SUB];
    int gid = blockIdx.x * 256 + threadIdx.x;
    int wave = gid >> 6;
    int lane = threadIdx.x & 63;
    int n = wave >> 2;
    int p = wave & 3;
    f4 xv = x4[(size_t)n * 64 + lane];
    f4 wv = w4[p * 64 + lane];
    if (p == 0) {
        ushort4 b;
        b.x = f2b(xv.x); b.y = f2b(xv.y); b.z = f2b(xv.z); b.w = f2b(xv.w);
        xb[(size_t)n * 64 + lane] = b;
    }
    f4 h = xv * wv;
    float ss = h.x * h.x + h.y * h.y + h.z * h.z + h.w * h.w;
    #pragma unroll
    for (int off = 32; off; off >>= 1) ss += __shfl_xor(ss, off);
    if (lane == 0) invn[n * 4 + p] = 1.0f / (sqrtf(ss) + 1e-12f);

    if (gid < N_TOTAL) row_fill[gid] = 0;
    if (gid == 0) *cnt = 0;

    if (blockIdx.x == 0) {
        int t = threadIdx.x;
        sv[t] = s[t];
        bv[t] = belong[t];
        __syncthreads();
        int myb = bv[t];
        float sum = 0.0f;
        for (int k = 0; k < K_SUB; ++k)
            if (bv[k] == myb) sum += sv[k];
        score[t] = sv[t] / sum;
    }
}

// ---- K2: raw edges -> fixed-capacity per-row buckets (no scan needed) ----
__global__ __launch_bounds__(256) void bucket_kernel(const int* __restrict__ re,
                                                     int* __restrict__ row_fill,
                                                     unsigned short* __restrict__ bucket) {
    int t = blockIdx.x * 256 + threadIdx.x;
    if (t < E_RAW) {
        int u = re[t];
        int v = re[E_RAW + t];
        int pos = atomicAdd(&row_fill[u], 1);
        if (pos < ROW_CAP) bucket[u * ROW_CAP + pos] = (unsigned short)v;
    }
}

// ---- K3: one block per output row ----
// (a) 8 immediate-zero dwordx4 stores (the whole row; no LDS, no load dep)
// (b) 32 masked-cosine edges (VALU+gathers overlap the store drain)
// (c) __syncthreads (vmcnt0: stores at L2) -> row's raw-edge atomics hit
//     still-L2-resident lines instead of random HBM RMW.
__global__ __launch_bounds__(256) void compose_kernel(f4* __restrict__ out4,
                                                      float* __restrict__ out,
                                                      const us8* __restrict__ xb8,
                                                      const f4* __restrict__ w4,
                                                      const int* __restrict__ fe,
                                                      const int* __restrict__ sel_batch,
                                                      const f4* __restrict__ invn4,
                                                      const float* __restrict__ score,
                                                      const int* __restrict__ row_fill,
                                                      const unsigned short* __restrict__ bucket,
                                                      int2* __restrict__ list,
                                                      int* __restrict__ cnt) {
    int b = blockIdx.x;                      // row id
    int t = threadIdx.x;
    int lane = t & 63;
    int l16  = lane & 15;
    int g    = lane >> 4;
    int w    = t >> 6;

    // (a) zero the row: 8 x 1KB-per-wave immediate stores
    size_t obase = (size_t)b * (N_TOTAL / 4);
    f4 z = (f4)0.0f;
    #pragma unroll
    for (int it = 0; it < 8; ++it)
        out4[obase + it * 256 + t] = z;

    // per-lane squared weights (dims [l16*16, l16*16+16), 4 perspectives)
    float q0[16], q1[16], q2[16], q3[16];
    #pragma unroll
    for (int gg = 0; gg < 4; ++gg) {
        f4 w0 = w4[0 * 64 + l16 * 4 + gg];
        f4 w1 = w4[1 * 64 + l16 * 4 + gg];
        f4 w2 = w4[2 * 64 + l16 * 4 + gg];
        f4 w3 = w4[3 * 64 + l16 * 4 + gg];
        q0[gg*4+0]=w0.x*w0.x; q0[gg*4+1]=w0.y*w0.y; q0[gg*4+2]=w0.z*w0.z; q0[gg*4+3]=w0.w*w0.w;
        q1[gg*4+0]=w1.x*w1.x; q1[gg*4+1]=w1.y*w1.y; q1[gg*4+2]=w1.z*w1.z; q1[gg*4+3]=w1.w*w1.w;
        q2[gg*4+0]=w2.x*w2.x; q2[gg*4+1]=w2.y*w2.y; q2[gg*4+2]=w2.z*w2.z; q2[gg*4+3]=w2.w*w2.w;
        q3[gg*4+0]=w3.x*w3.x; q3[gg*4+1]=w3.y*w3.y; q3[gg*4+2]=w3.z*w3.z; q3[gg*4+3]=w3.w*w3.w;
    }

    // (b) 32 masked-cosine edges for this block
    int ebase = b * 32 + w * 8;
    #pragma unroll
    for (int it = 0; it < 2; ++it) {
        int e = ebase + it * 4 + g;
        int i = fe[e];
        int j = fe[E_FULL + e];
        const us8* ri = xb8 + (size_t)i * 32;
        const us8* rj = xb8 + (size_t)j * 32;
        us8 xi0 = ri[2 * l16], xi1 = ri[2 * l16 + 1];
        us8 xj0 = rj[2 * l16], xj1 = rj[2 * l16 + 1];

        float a0 = 0.f, a1 = 0.f, a2 = 0.f, a3 = 0.f;
        #pragma unroll
        for (int k = 0; k < 8; ++k) {
            float p0 = B2F(xi0[k]) * B2F(xj0[k]);
            float p1 = B2F(xi1[k]) * B2F(xj1[k]);
            a0 = fmaf(p1, q0[k + 8], fmaf(p0, q0[k], a0));
            a1 = fmaf(p1, q1[k + 8], fmaf(p0, q1[k], a1));
            a2 = fmaf(p1, q2[k + 8], fmaf(p0, q2[k], a2));
            a3 = fmaf(p1, q3[k + 8], fmaf(p0, q3[k], a3));
        }
        f4 ii = invn4[i];
        f4 ij = invn4[j];
        float v = a0 * (ii.x * ij.x) + a1 * (ii.y * ij.y) +
                  a2 * (ii.z * ij.z) + a3 * (ii.w * ij.w);
        v += __shfl_xor(v, 1);
        v += __shfl_xor(v, 2);
        v += __shfl_xor(v, 4);
        v += __shfl_xor(v, 8);

        if (l16 == 0 && i != j) {
            v *= 0.25f;
            if (v > EPSILON) {
                float val = v * score[sel_batch[i]] * LAMB1;
                int idx = atomicAdd(cnt, 1);
                int2 ent;
                ent.x = (i << 13) | j;
                ent.y = __float_as_int(val);
                list[idx] = ent;
            }
        }
    }

    // (c) stores drained to L2 by the barrier's vmcnt(0); apply raw edges while
    //     this row's lines are still L2-resident (same XCD wrote them).
    __syncthreads();
    int rc = row_fill[b];
    if (rc > ROW_CAP) rc = ROW_CAP;
    const unsigned short* bk = bucket + b * ROW_CAP;
    for (int k = t; k < rc; k += 256)
        atomicAdd(&out[(size_t)b * N_TOTAL + bk[k]], 1.0f - LAMB1);
}

// ---- K4: dedup passing learned edges (mask .set semantics) + scatter ----
__global__ __launch_bounds__(256) void finalize_kernel(const int2* __restrict__ list,
                                                       const int* __restrict__ cnt,
                                                       const int* __restrict__ sel_map,
                                                       float* __restrict__ out) {
    int t = blockIdx.x * 256 + threadIdx.x;
    int n = *cnt;
    if (t >= n) return;
    int2 ek = list[t];
    for (int l = 0; l < t; ++l)
        if (list[l].x == ek.x) return;      // first occurrence wins; dups identical
    int i = ek.x >> 13;
    int j = ek.x & (N_SEL - 1);
    atomicAdd(&out[(size_t)sel_map[i] * N_TOTAL + sel_map[j]], __int_as_float(ek.y));
}

extern "C" void kernel_launch(void* const* d_in, const int* in_sizes, int n_in,
                              void* d_out, int out_size, void* d_ws, size_t ws_size,
                              hipStream_t stream) {
    const float* x         = (const float*)d_in[0];
    const float* mw        = (const float*)d_in[1];
    const int* sel_batch   = (const int*)d_in[2];
    const int* sel_map     = (const int*)d_in[3];
    const int* sel_belong  = (const int*)d_in[4];
    const float* sel_score = (const float*)d_in[5];
    const int* fe          = (const int*)d_in[6];
    const int* re          = (const int*)d_in[7];
    float* out             = (float*)d_out;

    char* ws        = (char*)d_ws;
    float* invn     = (float*)ws;
    float* score    = (float*)(ws + WS_SCORE_OFF);
    int* cnt        = (int*)(ws + WS_CNT_OFF);
    int* row_fill   = (int*)(ws + WS_FILL_OFF);
    ushort4* xb     = (ushort4*)(ws + WS_XB_OFF);
    unsigned short* bucket = (unsigned short*)(ws + WS_BUCKET_OFF);
    int2* list      = (int2*)(ws + WS_LIST_OFF);

    prep_kernel<<<8192, 256, 0, stream>>>(
        (const f4*)x, (const f4*)mw, invn, xb, sel_score, sel_belong, score,
        row_fill, cnt);
    bucket_kernel<<<E_RAW / 256, 256, 0, stream>>>(re, row_fill, bucket);
    compose_kernel<<<N_TOTAL, 256, 0, stream>>>(
        (f4*)out, out, (const us8*)xb, (const f4*)mw, fe, sel_batch,
        (const f4*)invn, score, row_fill, bucket, list, cnt);
    finalize_kernel<<<E_FULL / 256, 256, 0, stream>>>(list, cnt, sel_map, out);
}

// Round 7
// 97.629 us; speedup vs baseline: 1.2335x; 1.1241x over previous
//
#include <hip/hip_runtime.h>

typedef float f4 __attribute__((ext_vector_type(4)));
typedef unsigned short us8 __attribute__((ext_vector_type(8)));

#define N_SEL   8192
#define N_FEAT  256
#define K_SUB   256
#define N_PERS  4
#define E_FULL  262144
#define E_RAW   262144
#define N_TOTAL 8192
#define EPSILON 0.5f
#define LAMB1   0.5f

// Workspace layout:
#define WS_SCORE_OFF  (128 * 1024)                    // score[K_SUB] f32
#define WS_CNT_OFF    (132 * 1024)                    // pass counter i32
#define WS_XB_OFF     (256 * 1024)                    // xb[N_SEL][256] bf16 (4 MB)
#define WS_LIST_OFF   (WS_XB_OFF + 4 * 1024 * 1024)   // list[E_FULL] int2 (2 MB)

#define B2F(s) __uint_as_float(((unsigned)(s)) << 16)

static __device__ __forceinline__ unsigned short f2b(float f) {
    unsigned u = __float_as_uint(f);
    unsigned r = u + 0x7FFFu + ((u >> 16) & 1u);   // RNE
    return (unsigned short)(r >> 16);
}

// ---- K1: inverse norms + bf16 convert + score + cnt=0 ----
__global__ __launch_bounds__(256) void prep_kernel(const f4* __restrict__ x4,
                                                   const f4* __restrict__ w4,
                                                   float* __restrict__ invn,
                                                   ushort4* __restrict__ xb,
                                                   const float* __restrict__ s,
                                                   const int* __restrict__ belong,
                                                   float* __restrict__ score,
                                                   int* __restrict__ cnt) {
    __shared__ float sv[K_SUB];
    __shared__ int bv[K_SUB];
    int gid = blockIdx.x * 256 + threadIdx.x;
    int wave = gid >> 6;
    int lane = threadIdx.x & 63;
    int n = wave >> 2;
    int p = wave & 3;
    f4 xv = x4[(size_t)n * 64 + lane];
    f4 wv = w4[p * 64 + lane];
    if (p == 0) {
        ushort4 b;
        b.x = f2b(xv.x); b.y = f2b(xv.y); b.z = f2b(xv.z); b.w = f2b(xv.w);
        xb[(size_t)n * 64 + lane] = b;
    }
    f4 h = xv * wv;
    float ss = h.x * h.x + h.y * h.y + h.z * h.z + h.w * h.w;
    #pragma unroll
    for (int off = 32; off; off >>= 1) ss += __shfl_xor(ss, off);
    if (lane == 0) invn[n * 4 + p] = 1.0f / (sqrtf(ss) + 1e-12f);

    if (gid == 0) *cnt = 0;

    if (blockIdx.x == 0) {
        int t = threadIdx.x;
        sv[t] = s[t];
        bv[t] = belong[t];
        __syncthreads();
        int myb = bv[t];
        float sum = 0.0f;
        for (int k = 0; k < K_SUB; ++k)
            if (bv[k] == myb) sum += sv[k];
        score[t] = sv[t] / sum;
    }
}

// ---- K2: zero 4 output rows per block + 128 masked-cosine edges per block.
// NO barrier, NO vmcnt(0): waves issue stores, compute, exit — the 256 MB
// write stream drains continuously in the background. Stores interleaved
// 4-per-quad so in-order vmcnt retirement never parks a gather behind the
// whole store queue. Edge indices: 2 coalesced 128B loads per wave, then
// shfl-distributed. xb gathers double-buffered one quad ahead.
__global__ __launch_bounds__(256) void zero_edge_kernel(f4* __restrict__ out4,
                                                        const us8* __restrict__ xb8,
                                                        const f4* __restrict__ w4,
                                                        const int* __restrict__ fe,
                                                        const int* __restrict__ sel_batch,
                                                        const f4* __restrict__ invn4,
                                                        const float* __restrict__ score,
                                                        int2* __restrict__ list,
                                                        int* __restrict__ cnt) {
    int b = blockIdx.x;                  // 0..2047, owns rows [4b, 4b+4)
    int t = threadIdx.x;
    int lane = t & 63;
    int l16  = lane & 15;
    int sub  = lane >> 4;
    int w    = t >> 6;

    // this wave's 32 edges: lanes 0-31 hold i's, lanes 32-63 hold j's
    int ebase = b * 128 + w * 32;
    int myidx = (lane < 32) ? fe[ebase + lane] : fe[E_FULL + ebase + (lane - 32)];

    // per-lane squared weights (dims [l16*16, l16*16+16), 4 perspectives)
    float q0[16], q1[16], q2[16], q3[16];
    #pragma unroll
    for (int gg = 0; gg < 4; ++gg) {
        f4 w0 = w4[0 * 64 + l16 * 4 + gg];
        f4 w1 = w4[1 * 64 + l16 * 4 + gg];
        f4 w2 = w4[2 * 64 + l16 * 4 + gg];
        f4 w3 = w4[3 * 64 + l16 * 4 + gg];
        q0[gg*4+0]=w0.x*w0.x; q0[gg*4+1]=w0.y*w0.y; q0[gg*4+2]=w0.z*w0.z; q0[gg*4+3]=w0.w*w0.w;
        q1[gg*4+0]=w1.x*w1.x; q1[gg*4+1]=w1.y*w1.y; q1[gg*4+2]=w1.z*w1.z; q1[gg*4+3]=w1.w*w1.w;
        q2[gg*4+0]=w2.x*w2.x; q2[gg*4+1]=w2.y*w2.y; q2[gg*4+2]=w2.z*w2.z; q2[gg*4+3]=w2.w*w2.w;
        q3[gg*4+0]=w3.x*w3.x; q3[gg*4+1]=w3.y*w3.y; q3[gg*4+2]=w3.z*w3.z; q3[gg*4+3]=w3.w*w3.w;
    }

    // block owns 4 rows = 32768 floats = 8192 f4 (f4 units throughout!)
    size_t obase = (size_t)b * 8192;
    f4 z = (f4)0.0f;

    // prefetch quad 0
    int ci = __shfl(myidx, 0 + sub);
    int cj = __shfl(myidx, 32 + 0 + sub);
    const us8* ri = xb8 + (size_t)ci * 32;
    const us8* rj = xb8 + (size_t)cj * 32;
    us8 xi0 = ri[2 * l16], xi1 = ri[2 * l16 + 1];
    us8 xj0 = rj[2 * l16], xj1 = rj[2 * l16 + 1];

    #pragma unroll
    for (int q = 0; q < 8; ++q) {
        // 4 zero stores: block covers 1024 f4 = 16 KB per quad-step
        #pragma unroll
        for (int k = 0; k < 4; ++k)
            out4[obase + q * 1024 + k * 256 + t] = z;

        // rotate current quad into locals; prefetch next quad
        int i = ci, j = cj;
        us8 ai0 = xi0, ai1 = xi1, aj0 = xj0, aj1 = xj1;
        if (q < 7) {
            ci = __shfl(myidx, (q + 1) * 4 + sub);
            cj = __shfl(myidx, 32 + (q + 1) * 4 + sub);
            const us8* ri2 = xb8 + (size_t)ci * 32;
            const us8* rj2 = xb8 + (size_t)cj * 32;
            xi0 = ri2[2 * l16]; xi1 = ri2[2 * l16 + 1];
            xj0 = rj2[2 * l16]; xj1 = rj2[2 * l16 + 1];
        }

        float a0 = 0.f, a1 = 0.f, a2 = 0.f, a3 = 0.f;
        #pragma unroll
        for (int k = 0; k < 8; ++k) {
            float p0 = B2F(ai0[k]) * B2F(aj0[k]);
            float p1 = B2F(ai1[k]) * B2F(aj1[k]);
            a0 = fmaf(p1, q0[k + 8], fmaf(p0, q0[k], a0));
            a1 = fmaf(p1, q1[k + 8], fmaf(p0, q1[k], a1));
            a2 = fmaf(p1, q2[k + 8], fmaf(p0, q2[k], a2));
            a3 = fmaf(p1, q3[k + 8], fmaf(p0, q3[k], a3));
        }
        f4 ii = invn4[i];
        f4 ij = invn4[j];
        float v = a0 * (ii.x * ij.x) + a1 * (ii.y * ij.y) +
                  a2 * (ii.z * ij.z) + a3 * (ii.w * ij.w);
        v += __shfl_xor(v, 1);
        v += __shfl_xor(v, 2);
        v += __shfl_xor(v, 4);
        v += __shfl_xor(v, 8);

        if (l16 == 0 && i != j) {
            v *= 0.25f;
            if (v > EPSILON) {
                float val = v * score[sel_batch[i]] * LAMB1;
                int idx = atomicAdd(cnt, 1);
                int2 ent;
                ent.x = (i << 13) | j;
                ent.y = __float_as_int(val);
                list[idx] = ent;
            }
        }
    }
}

// ---- K3: raw-edge atomics (ordered after K2's zeros by stream/graph
//          dependency) + dedup'd learned-edge scatter ----
__global__ __launch_bounds__(256) void raw_finalize_kernel(const int* __restrict__ re,
                                                           const int2* __restrict__ list,
                                                           const int* __restrict__ cnt,
                                                           const int* __restrict__ sel_map,
                                                           float* __restrict__ out) {
    int t = blockIdx.x * 256 + threadIdx.x;
    if (t < E_RAW) {
        int u = re[t];
        int v = re[E_RAW + t];
        atomicAdd(&out[(size_t)u * N_TOTAL + v], 1.0f - LAMB1);
    }
    int n = *cnt;
    if (t < n) {
        int2 ek = list[t];
        bool first = true;
        for (int l = 0; l < t; ++l)
            if (list[l].x == ek.x) { first = false; break; }
        if (first) {
            int i = ek.x >> 13;
            int j = ek.x & (N_SEL - 1);
            atomicAdd(&out[(size_t)sel_map[i] * N_TOTAL + sel_map[j]],
                      __int_as_float(ek.y));
        }
    }
}

extern "C" void kernel_launch(void* const* d_in, const int* in_sizes, int n_in,
                              void* d_out, int out_size, void* d_ws, size_t ws_size,
                              hipStream_t stream) {
    const float* x         = (const float*)d_in[0];
    const float* mw        = (const float*)d_in[1];
    const int* sel_batch   = (const int*)d_in[2];
    const int* sel_map     = (const int*)d_in[3];
    const int* sel_belong  = (const int*)d_in[4];
    const float* sel_score = (const float*)d_in[5];
    const int* fe          = (const int*)d_in[6];
    const int* re          = (const int*)d_in[7];
    float* out             = (float*)d_out;

    char* ws       = (char*)d_ws;
    float* invn    = (float*)ws;
    float* score   = (float*)(ws + WS_SCORE_OFF);
    int* cnt       = (int*)(ws + WS_CNT_OFF);
    ushort4* xb    = (ushort4*)(ws + WS_XB_OFF);
    int2* list     = (int2*)(ws + WS_LIST_OFF);

    prep_kernel<<<8192, 256, 0, stream>>>(
        (const f4*)x, (const f4*)mw, invn, xb, sel_score, sel_belong, score, cnt);
    zero_edge_kernel<<<2048, 256, 0, stream>>>(
        (f4*)out, (const us8*)xb, (const f4*)mw, fe, sel_batch,
        (const f4*)invn, score, list, cnt);
    raw_finalize_kernel<<<1024, 256, 0, stream>>>(re, list, cnt, sel_map, out);
}

// Round 9
// 89.268 us; speedup vs baseline: 1.3490x; 1.0937x over previous
//
#include <hip/hip_runtime.h>

typedef float f4 __attribute__((ext_vector_type(4)));

#define N_SEL   8192
#define N_FEAT  256
#define K_SUB   256
#define N_PERS  4
#define E_FULL  262144
#define E_RAW   262144
#define N_TOTAL 8192
#define EPSILON 0.5f
#define LAMB1   0.5f

// Workspace layout:
#define WS_SCORE_OFF  (128 * 1024)                    // score[K_SUB] f32
#define WS_CNT_OFF    (132 * 1024)                    // pass counter i32
#define WS_XQ_OFF     (256 * 1024)                    // xq[N_SEL][256] fp8 (2 MB)
#define WS_LIST_OFF   (WS_XQ_OFF + 2 * 1024 * 1024)   // list[E_FULL] int2 (2 MB)

// ---- K1: inverse norms + fp8 convert + score + cnt=0 ----
__global__ __launch_bounds__(256) void prep_kernel(const f4* __restrict__ x4,
                                                   const f4* __restrict__ w4,
                                                   float* __restrict__ invn,
                                                   unsigned int* __restrict__ xq,
                                                   const float* __restrict__ s,
                                                   const int* __restrict__ belong,
                                                   float* __restrict__ score,
                                                   int* __restrict__ cnt) {
    __shared__ float sv[K_SUB];
    __shared__ int bv[K_SUB];
    int gid = blockIdx.x * 256 + threadIdx.x;
    int wave = gid >> 6;
    int lane = threadIdx.x & 63;
    int n = wave >> 2;
    int p = wave & 3;
    f4 xv = x4[(size_t)n * 64 + lane];
    f4 wv = w4[p * 64 + lane];
    if (p == 0) {
        // pack 4 dims to 4 fp8 bytes (HW RNE); lane covers dims [4*lane, 4*lane+4)
        int pk = 0;
        pk = __builtin_amdgcn_cvt_pk_fp8_f32(xv.x, xv.y, pk, false);
        pk = __builtin_amdgcn_cvt_pk_fp8_f32(xv.z, xv.w, pk, true);
        xq[(size_t)n * 64 + lane] = (unsigned int)pk;
    }
    f4 h = xv * wv;
    float ss = h.x * h.x + h.y * h.y + h.z * h.z + h.w * h.w;
    #pragma unroll
    for (int off = 32; off; off >>= 1) ss += __shfl_xor(ss, off);
    if (lane == 0) invn[n * 4 + p] = 1.0f / (sqrtf(ss) + 1e-12f);

    if (gid == 0) *cnt = 0;

    if (blockIdx.x == 0) {
        int t = threadIdx.x;
        sv[t] = s[t];
        bv[t] = belong[t];
        __syncthreads();
        int myb = bv[t];
        float sum = 0.0f;
        for (int k = 0; k < K_SUB; ++k)
            if (bv[k] == myb) sum += sv[k];
        score[t] = sv[t] / sum;
    }
}

// ---- K2: zero 1 output row per wave (32x 1KB stores) + 32 cosine edges per
// wave, interleaved 1:1. 64 lanes per edge: one dword (4 fp8 dims) per lane
// per side -> 2 gathers/edge; w^2 table is 16 VGPRs -> high occupancy, so
// gather latency multiplexes under the continuous store stream. No barrier,
// no vmcnt(0) drain.
__global__ __launch_bounds__(256) void zero_edge_kernel(f4* __restrict__ out4,
                                                        const unsigned int* __restrict__ xq,
                                                        const f4* __restrict__ w4,
                                                        const int* __restrict__ fe,
                                                        const int* __restrict__ sel_batch,
                                                        const f4* __restrict__ invn4,
                                                        const float* __restrict__ score,
                                                        int2* __restrict__ list,
                                                        int* __restrict__ cnt) {
    int b = blockIdx.x;                  // 0..2047; block owns rows [4b, 4b+4)
    int t = threadIdx.x;
    int lane = t & 63;
    int w = t >> 6;

    // wave's 32 edges: lanes 0-31 hold i's, lanes 32-63 hold j's
    int ebase = b * 128 + w * 32;
    int myidx = (lane < 32) ? fe[ebase + lane] : fe[E_FULL + ebase + (lane - 32)];

    // per-lane squared weights for dims [4*lane, 4*lane+4), 4 perspectives
    f4 q0 = w4[0 * 64 + lane]; q0 *= q0;
    f4 q1 = w4[1 * 64 + lane]; q1 *= q1;
    f4 q2 = w4[2 * 64 + lane]; q2 *= q2;
    f4 q3 = w4[3 * 64 + lane]; q3 *= q3;

    size_t obase = (size_t)(b * 4 + w) * 2048;   // row base in f4 units
    f4 z = (f4)0.0f;

    // prefetch edge 0
    int ci = __shfl(myidx, 0);
    int cj = __shfl(myidx, 32);
    unsigned int xi = xq[(size_t)ci * 64 + lane];
    unsigned int xj = xq[(size_t)cj * 64 + lane];
    f4 ii = invn4[ci];
    f4 ij = invn4[cj];

    #pragma unroll 4
    for (int s = 0; s < 32; ++s) {
        // one 1KB zero store per step; 32 steps cover the wave's row
        out4[obase + s * 64 + lane] = z;

        // rotate current edge into locals; prefetch next
        int i = ci, j = cj;
        unsigned int ax = xi, bx = xj;
        f4 aii = ii, aij = ij;
        if (s < 31) {
            ci = __shfl(myidx, s + 1);
            cj = __shfl(myidx, 32 + s + 1);
            xi = xq[(size_t)ci * 64 + lane];
            xj = xq[(size_t)cj * 64 + lane];
            ii = invn4[ci];
            ij = invn4[cj];
        }

        // decode fp8 dims (literal selectors required by the builtin)
        float pd0 = __builtin_amdgcn_cvt_f32_fp8((int)ax, 0) *
                    __builtin_amdgcn_cvt_f32_fp8((int)bx, 0);
        float pd1 = __builtin_amdgcn_cvt_f32_fp8((int)ax, 1) *
                    __builtin_amdgcn_cvt_f32_fp8((int)bx, 1);
        float pd2 = __builtin_amdgcn_cvt_f32_fp8((int)ax, 2) *
                    __builtin_amdgcn_cvt_f32_fp8((int)bx, 2);
        float pd3 = __builtin_amdgcn_cvt_f32_fp8((int)ax, 3) *
                    __builtin_amdgcn_cvt_f32_fp8((int)bx, 3);

        float a0 = fmaf(pd3, q0.w, fmaf(pd2, q0.z, fmaf(pd1, q0.y, pd0 * q0.x)));
        float a1 = fmaf(pd3, q1.w, fmaf(pd2, q1.z, fmaf(pd1, q1.y, pd0 * q1.x)));
        float a2 = fmaf(pd3, q2.w, fmaf(pd2, q2.z, fmaf(pd1, q2.y, pd0 * q2.x)));
        float a3 = fmaf(pd3, q3.w, fmaf(pd2, q3.z, fmaf(pd1, q3.y, pd0 * q3.x)));

        float v = a0 * (aii.x * aij.x) + a1 * (aii.y * aij.y) +
                  a2 * (aii.z * aij.z) + a3 * (aii.w * aij.w);
        v += __shfl_xor(v, 1);
        v += __shfl_xor(v, 2);
        v += __shfl_xor(v, 4);
        v += __shfl_xor(v, 8);
        v += __shfl_xor(v, 16);
        v += __shfl_xor(v, 32);

        if (lane == 0 && i != j) {
            v *= 0.25f;
            if (v > EPSILON) {
                float val = v * score[sel_batch[i]] * LAMB1;
                int idx = atomicAdd(cnt, 1);
                int2 ent;
                ent.x = (i << 13) | j;
                ent.y = __float_as_int(val);
                list[idx] = ent;
            }
        }
    }
}

// ---- K3: raw-edge atomics (ordered after K2 by stream dependency) +
//          dedup'd learned-edge scatter ----
__global__ __launch_bounds__(256) void raw_finalize_kernel(const int* __restrict__ re,
                                                           const int2* __restrict__ list,
                                                           const int* __restrict__ cnt,
                                                           const int* __restrict__ sel_map,
                                                           float* __restrict__ out) {
    int t = blockIdx.x * 256 + threadIdx.x;
    if (t < E_RAW) {
        int u = re[t];
        int v = re[E_RAW + t];
        atomicAdd(&out[(size_t)u * N_TOTAL + v], 1.0f - LAMB1);
    }
    int n = *cnt;
    if (t < n) {
        int2 ek = list[t];
        bool first = true;
        for (int l = 0; l < t; ++l)
            if (list[l].x == ek.x) { first = false; break; }
        if (first) {
            int i = ek.x >> 13;
            int j = ek.x & (N_SEL - 1);
            atomicAdd(&out[(size_t)sel_map[i] * N_TOTAL + sel_map[j]],
                      __int_as_float(ek.y));
        }
    }
}

extern "C" void kernel_launch(void* const* d_in, const int* in_sizes, int n_in,
                              void* d_out, int out_size, void* d_ws, size_t ws_size,
                              hipStream_t stream) {
    const float* x         = (const float*)d_in[0];
    const float* mw        = (const float*)d_in[1];
    const int* sel_batch   = (const int*)d_in[2];
    const int* sel_map     = (const int*)d_in[3];
    const int* sel_belong  = (const int*)d_in[4];
    const float* sel_score = (const float*)d_in[5];
    const int* fe          = (const int*)d_in[6];
    const int* re          = (const int*)d_in[7];
    float* out             = (float*)d_out;

    char* ws         = (char*)d_ws;
    float* invn      = (float*)ws;
    float* score     = (float*)(ws + WS_SCORE_OFF);
    int* cnt         = (int*)(ws + WS_CNT_OFF);
    unsigned int* xq = (unsigned int*)(ws + WS_XQ_OFF);
    int2* list       = (int2*)(ws + WS_LIST_OFF);

    prep_kernel<<<8192, 256, 0, stream>>>(
        (const f4*)x, (const f4*)mw, invn, xq, sel_score, sel_belong, score, cnt);
    zero_edge_kernel<<<2048, 256, 0, stream>>>(
        (f4*)out, xq, (const f4*)mw, fe, sel_batch,
        (const f4*)invn, score, list, cnt);
    raw_finalize_kernel<<<1024, 256, 0, stream>>>(re, list, cnt, sel_map, out);
}